// Round 2
// baseline (279.826 us; speedup 1.0000x reference)
//
#include <hip/hip_runtime.h>
#include <hip/hip_bf16.h>
#include <math.h>
#include <stdint.h>

#define B_ROWS 2048
#define D_DIM  512
#define V_COLS 32000
#define BM 128
#define BN 128
#define BK 64
#define KSTEPS (D_DIM / BK)             // 8
#define NPART  ((V_COLS / BN) * 2)      // 500 partials per row (2 wave-cols per block)
#define S_SC   30.0f
#define COS_M  0.8775825618903728f      // cos(0.5)
#define SIN_M  0.479425538604203f       // sin(0.5)

typedef __bf16 bf16x8 __attribute__((ext_vector_type(8)));
typedef float  f32x4  __attribute__((ext_vector_type(4)));

// ---------- helpers ----------
__device__ __forceinline__ unsigned short f2bf(float f) {
  union { float f; unsigned u; } v; v.f = f;
  unsigned r = v.u + 0x7fffu + ((v.u >> 16) & 1u);   // round-nearest-even
  return (unsigned short)(r >> 16);
}

// async global->LDS, 16B per lane. LDS dest is wave-uniform base + lane*16.
__device__ __forceinline__ void load16_to_lds(const void* g, void* l) {
  __builtin_amdgcn_global_load_lds(
      (__attribute__((address_space(1))) void*)(g),
      (__attribute__((address_space(3))) void*)(l),
      16, 0, 0);
}

// ---------- kernel 1: fused row L2-normalize (x then W) fp32 -> bf16, + zero d_out ----------
// grid = (B_ROWS + V_COLS) / 4 blocks of 256; 1 wave per row (D=512).
__global__ void fused_norm_kernel(const float* __restrict__ x,
                                  const float* __restrict__ W,
                                  unsigned short* __restrict__ nx,
                                  unsigned short* __restrict__ nw,
                                  float* __restrict__ out) {
  if (blockIdx.x == 0 && threadIdx.x == 0) out[0] = 0.f;   // reduce kernel runs later in-stream
  const int lane = threadIdx.x & 63;
  const int wave = threadIdx.x >> 6;
  const int gr   = blockIdx.x * 4 + wave;
  const float* src;
  unsigned short* dst;
  if (gr < B_ROWS) {
    src = x + (size_t)gr * D_DIM;
    dst = nx + (size_t)gr * D_DIM;
  } else {
    src = W + (size_t)(gr - B_ROWS) * D_DIM;
    dst = nw + (size_t)(gr - B_ROWS) * D_DIM;
  }
  const float4* r4 = (const float4*)src;
  float4 v0 = r4[lane];
  float4 v1 = r4[64 + lane];
  float ss = v0.x*v0.x + v0.y*v0.y + v0.z*v0.z + v0.w*v0.w
           + v1.x*v1.x + v1.y*v1.y + v1.z*v1.z + v1.w*v1.w;
  #pragma unroll
  for (int off = 32; off >= 1; off >>= 1) ss += __shfl_xor(ss, off, 64);
  float inv = 1.0f / fmaxf(sqrtf(ss), 1e-12f);
  ushort4 o0, o1;
  o0.x = f2bf(v0.x*inv); o0.y = f2bf(v0.y*inv); o0.z = f2bf(v0.z*inv); o0.w = f2bf(v0.w*inv);
  o1.x = f2bf(v1.x*inv); o1.y = f2bf(v1.y*inv); o1.z = f2bf(v1.z*inv); o1.w = f2bf(v1.w*inv);
  ushort4* d4 = (ushort4*)dst;
  d4[lane]      = o0;
  d4[64 + lane] = o1;
}

// ---------- kernel 2: bf16 GEMM (nx @ nW^T) fused with label-phi + per-slice softmax partials ----------
// grid = (B_ROWS/BM = 16 row-tiles [fastest], V_COLS/BN = 250 col-tiles) -> concurrent
// blocks share nw col-tiles in L2/L3 (cuts HBM re-fetch of nw from 16x to ~1x).
// LDS layout: 16B chunks XOR-swizzled within each row (slot j holds global chunk j^(r&7))
// so ds_read_b128 by 16 consecutive rows tiles all 32 banks (<=2-way aliasing = free).
__global__ __launch_bounds__(256)
void arc_gemm_kernel(const unsigned short* __restrict__ nx,
                     const unsigned short* __restrict__ nw,
                     const int* __restrict__ labels,
                     float* __restrict__ pmax,
                     float* __restrict__ psum,
                     float* __restrict__ lbl_logit) {
  __shared__ unsigned short sA[BM * BK];   // 16 KB
  __shared__ unsigned short sB[BN * BK];   // 16 KB

  const int tid  = threadIdx.x;            // 0..255
  const int wave = tid >> 6;               // 0..3
  const int lane = tid & 63;
  const int wm   = wave >> 1;              // wave row-half (64 rows)
  const int wn   = wave & 1;               // wave col-half (64 cols)
  const int quad = lane >> 4;              // 0..3
  const int l16  = lane & 15;
  const int m0   = blockIdx.x * BM;        // row tile (fastest-varying)
  const int n0   = blockIdx.y * BN;        // col tile

  f32x4 acc[4][4];
  #pragma unroll
  for (int i = 0; i < 4; ++i)
    #pragma unroll
    for (int j = 0; j < 4; ++j) acc[i][j] = (f32x4){0.f, 0.f, 0.f, 0.f};

  for (int ks = 0; ks < KSTEPS; ++ks) {
    __syncthreads();   // previous compute done before overwriting LDS
    #pragma unroll
    for (int i = 0; i < 4; ++i) {
      const int chunk = i * 256 + tid;       // LDS slot index: 1024 slots = 128 rows * 8 chunks
      const int r     = chunk >> 3;
      const int js    = chunk & 7;           // LDS slot col
      const int jg    = js ^ (r & 7);        // global chunk col (XOR swizzle)
      const unsigned short* ga = nx + (size_t)(m0 + r) * D_DIM + ks * BK + jg * 8;
      const unsigned short* gb = nw + (size_t)(n0 + r) * D_DIM + ks * BK + jg * 8;
      load16_to_lds(ga, &sA[(i * 256 + wave * 64) * 8]);
      load16_to_lds(gb, &sB[(i * 256 + wave * 64) * 8]);
    }
    __syncthreads();   // tiles resident

    #pragma unroll
    for (int h = 0; h < 2; ++h) {            // K-halves: k = h*32 .. h*32+31
      bf16x8 af[4], bfr[4];
      const int jq = quad + h * 4;           // global chunk col for this lane's K-block
      #pragma unroll
      for (int mi = 0; mi < 4; ++mi) {
        const int r = wm * 64 + mi * 16 + l16;
        af[mi] = *(const bf16x8*)&sA[r * BK + ((jq ^ (r & 7)) << 3)];
      }
      #pragma unroll
      for (int ni = 0; ni < 4; ++ni) {
        const int r = wn * 64 + ni * 16 + l16;
        bfr[ni] = *(const bf16x8*)&sB[r * BK + ((jq ^ (r & 7)) << 3)];
      }
      #pragma unroll
      for (int mi = 0; mi < 4; ++mi)
        #pragma unroll
        for (int ni = 0; ni < 4; ++ni)
          acc[mi][ni] = __builtin_amdgcn_mfma_f32_16x16x32_bf16(af[mi], bfr[ni], acc[mi][ni], 0, 0, 0);
    }
  }

  // Epilogue. C/D layout: col = lane&15, row = quad*4 + reg.
  const int pidx = blockIdx.y * 2 + wn;
  #pragma unroll
  for (int mi = 0; mi < 4; ++mi) {
    #pragma unroll
    for (int r = 0; r < 4; ++r) {
      const int grow = m0 + wm * 64 + mi * 16 + quad * 4 + r;
      const int lbl  = labels[grow];
      float vals[4];
      #pragma unroll
      for (int ni = 0; ni < 4; ++ni) {
        float c = acc[mi][ni][r];
        const int gcol = n0 + wn * 64 + ni * 16 + l16;
        if (gcol == lbl) {
          float sy  = sqrtf(fminf(1.f, fmaxf(0.f, 1.f - c * c)));
          float phi = c * COS_M - sy * SIN_M;
          lbl_logit[grow] = S_SC * phi;   // exactly one lane grid-wide hits this
          c = phi;
        }
        vals[ni] = S_SC * c;
      }
      // row max across the 16 lanes of this quad, THEN one exp pass (4 exps not 12)
      float vmax = fmaxf(fmaxf(vals[0], vals[1]), fmaxf(vals[2], vals[3]));
      #pragma unroll
      for (int off = 1; off < 16; off <<= 1)
        vmax = fmaxf(vmax, __shfl_xor(vmax, off, 64));
      float vsum = __expf(vals[0] - vmax) + __expf(vals[1] - vmax)
                 + __expf(vals[2] - vmax) + __expf(vals[3] - vmax);
      #pragma unroll
      for (int off = 1; off < 16; off <<= 1)
        vsum += __shfl_xor(vsum, off, 64);
      if (l16 == 0) {
        pmax[(size_t)grow * NPART + pidx] = vmax;
        psum[(size_t)grow * NPART + pidx] = vsum;
      }
    }
  }
}

// ---------- kernel 3: merge partials -> loss ----------
__global__ void arc_reduce_kernel(const float* __restrict__ pmax,
                                  const float* __restrict__ psum,
                                  const float* __restrict__ lbl_logit,
                                  float* __restrict__ out) {
  const int row  = blockIdx.x;
  const int lane = threadIdx.x;   // 64 threads
  const float* pm = pmax + (size_t)row * NPART;
  const float* ps = psum + (size_t)row * NPART;
  float m = -1e30f, s = 0.f;
  for (int p = lane; p < NPART; p += 64) {
    float om = pm[p], os = ps[p];
    float nm = fmaxf(m, om);
    s = s * __expf(m - nm) + os * __expf(om - nm);
    m = nm;
  }
  #pragma unroll
  for (int off = 32; off >= 1; off >>= 1) {
    float om = __shfl_xor(m, off, 64);
    float os = __shfl_xor(s, off, 64);
    float nm = fmaxf(m, om);
    s = s * __expf(m - nm) + os * __expf(om - nm);
    m = nm;
  }
  if (lane == 0) {
    float lse = m + logf(s);
    atomicAdd(out, (lse - lbl_logit[row]) * (1.0f / (float)B_ROWS));
  }
}

// ---------- launch ----------
extern "C" void kernel_launch(void* const* d_in, const int* in_sizes, int n_in,
                              void* d_out, int out_size, void* d_ws, size_t ws_size,
                              hipStream_t stream) {
  const float* x      = (const float*)d_in[0];
  const float* W      = (const float*)d_in[1];
  const int*   labels = (const int*)d_in[2];
  float* out = (float*)d_out;

  char* ws = (char*)d_ws;
  unsigned short* nx = (unsigned short*)ws;                                   // 2 MB
  unsigned short* nw = (unsigned short*)(ws + (size_t)B_ROWS * D_DIM * 2);    // 32.75 MB
  char* p = ws + (size_t)B_ROWS * D_DIM * 2 + (size_t)V_COLS * D_DIM * 2;
  float* pmax = (float*)p;  p += (size_t)B_ROWS * NPART * 4;                  // 4.1 MB
  float* psum = (float*)p;  p += (size_t)B_ROWS * NPART * 4;                  // 4.1 MB
  float* lbl_logit = (float*)p;                                               // 8 KB

  hipLaunchKernelGGL(fused_norm_kernel, dim3((B_ROWS + V_COLS) / 4), dim3(256), 0, stream,
                     x, W, nx, nw, out);
  hipLaunchKernelGGL(arc_gemm_kernel, dim3(B_ROWS / BM, V_COLS / BN), dim3(256), 0, stream,
                     nx, nw, labels, pmax, psum, lbl_logit);
  hipLaunchKernelGGL(arc_reduce_kernel, dim3(B_ROWS), dim3(64), 0, stream,
                     pmax, psum, lbl_logit, out);
}

// Round 3
// 255.514 us; speedup vs baseline: 1.0952x; 1.0952x over previous
//
#include <hip/hip_runtime.h>
#include <hip/hip_bf16.h>
#include <math.h>
#include <stdint.h>

#define B_ROWS 2048
#define D_DIM  512
#define V_COLS 32000
#define BM 128
#define BN 128
#define BK 32
#define KSTEPS (D_DIM / BK)             // 16
#define NCT    (V_COLS / BN)            // 250 col tiles
#define NRT    (B_ROWS / BM)            // 16 row tiles
#define NPART  (NCT * 2)                // 500 partials per row
#define S_SC   30.0f
#define COS_M  0.8775825618903728f      // cos(0.5)
#define SIN_M  0.479425538604203f       // sin(0.5)

typedef __bf16 bf16x8 __attribute__((ext_vector_type(8)));
typedef float  f32x4  __attribute__((ext_vector_type(4)));

// ---------- helpers ----------
__device__ __forceinline__ unsigned short f2bf(float f) {
  union { float f; unsigned u; } v; v.f = f;
  unsigned r = v.u + 0x7fffu + ((v.u >> 16) & 1u);   // round-nearest-even
  return (unsigned short)(r >> 16);
}

// async global->LDS, 16B per lane. LDS dest is wave-uniform base + lane*16.
__device__ __forceinline__ void load16_to_lds(const void* g, void* l) {
  __builtin_amdgcn_global_load_lds(
      (__attribute__((address_space(1))) void*)(g),
      (__attribute__((address_space(3))) void*)(l),
      16, 0, 0);
}

// ---------- kernel 1: fused row L2-normalize (x then W) fp32 -> bf16, + zero d_out ----------
__global__ void fused_norm_kernel(const float* __restrict__ x,
                                  const float* __restrict__ W,
                                  unsigned short* __restrict__ nx,
                                  unsigned short* __restrict__ nw,
                                  float* __restrict__ out) {
  if (blockIdx.x == 0 && threadIdx.x == 0) out[0] = 0.f;
  const int lane = threadIdx.x & 63;
  const int wave = threadIdx.x >> 6;
  const int gr   = blockIdx.x * 4 + wave;
  const float* src;
  unsigned short* dst;
  if (gr < B_ROWS) {
    src = x + (size_t)gr * D_DIM;
    dst = nx + (size_t)gr * D_DIM;
  } else {
    src = W + (size_t)(gr - B_ROWS) * D_DIM;
    dst = nw + (size_t)(gr - B_ROWS) * D_DIM;
  }
  const float4* r4 = (const float4*)src;
  float4 v0 = r4[lane];
  float4 v1 = r4[64 + lane];
  float ss = v0.x*v0.x + v0.y*v0.y + v0.z*v0.z + v0.w*v0.w
           + v1.x*v1.x + v1.y*v1.y + v1.z*v1.z + v1.w*v1.w;
  #pragma unroll
  for (int off = 32; off >= 1; off >>= 1) ss += __shfl_xor(ss, off, 64);
  float inv = 1.0f / fmaxf(sqrtf(ss), 1e-12f);
  ushort4 o0, o1;
  o0.x = f2bf(v0.x*inv); o0.y = f2bf(v0.y*inv); o0.z = f2bf(v0.z*inv); o0.w = f2bf(v0.w*inv);
  o1.x = f2bf(v1.x*inv); o1.y = f2bf(v1.y*inv); o1.z = f2bf(v1.z*inv); o1.w = f2bf(v1.w*inv);
  ushort4* d4 = (ushort4*)dst;
  d4[lane]      = o0;
  d4[64 + lane] = o1;
}

// ---------- kernel 2: bf16 GEMM (nx @ nW^T) + label-phi + per-slice softmax partials ----------
// Grid: 1D 4096 blocks; id -> (rt fastest within XCD, XCD-exclusive col tiles):
//   k = id&7 (XCD under id%8 round-robin), q = id>>3, rt = q&15, ct = (q>>4)*8 + k.
//   Each XCD owns distinct col tiles -> its nw tile stays L2-hot across 16 row tiles;
//   nx (2 MB) stays L2-resident. ct>=250 blocks (96 of 4096) exit.
// LDS: BK=32 (16 KB total, 4 blocks/CU with 64 VGPR+64 AGPR), 16B chunks XOR-swizzled:
//   slot js of row r holds global chunk js ^ ((r>>1)&3) -> ds_read_b128 by a quad's 16
//   lanes covers all 8 bank-quads 2-way (free, validated by R2's zero-conflict result).
__global__ __launch_bounds__(256)
void arc_gemm_kernel(const unsigned short* __restrict__ nx,
                     const unsigned short* __restrict__ nw,
                     const int* __restrict__ labels,
                     float* __restrict__ pmax,
                     float* __restrict__ psum,
                     float* __restrict__ lbl_logit) {
  __shared__ unsigned short sA[BM * BK];   // 8 KB
  __shared__ unsigned short sB[BN * BK];   // 8 KB

  const int id = blockIdx.x;
  const int ct = ((id >> 7) << 3) | (id & 7);
  if (ct >= NCT) return;
  const int rt = (id >> 3) & 15;
  const int m0 = rt * BM;
  const int n0 = ct * BN;

  const int tid  = threadIdx.x;            // 0..255
  const int wave = tid >> 6;               // 0..3
  const int lane = tid & 63;
  const int wm   = wave >> 1;              // wave row-half (64 rows)
  const int wn   = wave & 1;               // wave col-half (64 cols)
  const int quad = lane >> 4;              // 0..3
  const int l16  = lane & 15;

  // staging: thread handles rows {sr, 64+sr}, slot col js; fetches global chunk jg
  const int js = tid & 3;
  const int sr = tid >> 2;                 // 0..63
  const int jg = js ^ ((sr >> 1) & 3);     // i-invariant and ks-invariant
  const unsigned short* gA = nx + (size_t)(m0 + sr) * D_DIM + jg * 8;
  const unsigned short* gB = nw + (size_t)(n0 + sr) * D_DIM + jg * 8;
  unsigned short* ldsA0 = &sA[(wave * 64) * 8];          // wave-uniform dests
  unsigned short* ldsA1 = &sA[(256 + wave * 64) * 8];
  unsigned short* ldsB0 = &sB[(wave * 64) * 8];
  unsigned short* ldsB1 = &sB[(256 + wave * 64) * 8];

  // fragment-load swizzle: lane-constant slot col
  const int swl = (l16 >> 1) & 3;
  const int cSlot = (quad ^ swl) << 3;     // element offset within row

  f32x4 acc[4][4];
  #pragma unroll
  for (int i = 0; i < 4; ++i)
    #pragma unroll
    for (int j = 0; j < 4; ++j) acc[i][j] = (f32x4){0.f, 0.f, 0.f, 0.f};

  for (int ks = 0; ks < KSTEPS; ++ks) {
    __syncthreads();   // previous compute done before overwriting LDS
    {
      const size_t ko = (size_t)(ks * BK);
      load16_to_lds(gA + ko, ldsA0);
      load16_to_lds(gA + 64 * D_DIM + ko, ldsA1);
      load16_to_lds(gB + ko, ldsB0);
      load16_to_lds(gB + 64 * D_DIM + ko, ldsB1);
    }
    __syncthreads();   // tiles resident

    bf16x8 af[4], bfr[4];
    #pragma unroll
    for (int mi = 0; mi < 4; ++mi)
      af[mi] = *(const bf16x8*)&sA[(wm * 64 + mi * 16 + l16) * BK + cSlot];
    #pragma unroll
    for (int ni = 0; ni < 4; ++ni)
      bfr[ni] = *(const bf16x8*)&sB[(wn * 64 + ni * 16 + l16) * BK + cSlot];
    #pragma unroll
    for (int mi = 0; mi < 4; ++mi)
      #pragma unroll
      for (int ni = 0; ni < 4; ++ni)
        acc[mi][ni] = __builtin_amdgcn_mfma_f32_16x16x32_bf16(af[mi], bfr[ni], acc[mi][ni], 0, 0, 0);
  }

  // Epilogue. C/D layout: col = lane&15, row = quad*4 + reg.
  const int pidx = ct * 2 + wn;
  #pragma unroll
  for (int mi = 0; mi < 4; ++mi) {
    #pragma unroll
    for (int r = 0; r < 4; ++r) {
      const int grow = m0 + wm * 64 + mi * 16 + quad * 4 + r;
      const int lbl  = labels[grow];
      float vals[4];
      #pragma unroll
      for (int ni = 0; ni < 4; ++ni) {
        float c = acc[mi][ni][r];
        const int gcol = n0 + wn * 64 + ni * 16 + l16;
        if (gcol == lbl) {
          float sy  = sqrtf(fminf(1.f, fmaxf(0.f, 1.f - c * c)));
          float phi = c * COS_M - sy * SIN_M;
          lbl_logit[grow] = S_SC * phi;   // exactly one lane grid-wide hits this
          c = phi;
        }
        vals[ni] = S_SC * c;
      }
      // max first across the quad's 16 lanes, then one exp pass (4 exps not 12)
      float vmax = fmaxf(fmaxf(vals[0], vals[1]), fmaxf(vals[2], vals[3]));
      #pragma unroll
      for (int off = 1; off < 16; off <<= 1)
        vmax = fmaxf(vmax, __shfl_xor(vmax, off, 64));
      float vsum = __expf(vals[0] - vmax) + __expf(vals[1] - vmax)
                 + __expf(vals[2] - vmax) + __expf(vals[3] - vmax);
      #pragma unroll
      for (int off = 1; off < 16; off <<= 1)
        vsum += __shfl_xor(vsum, off, 64);
      if (l16 == 0) {
        pmax[(size_t)grow * NPART + pidx] = vmax;
        psum[(size_t)grow * NPART + pidx] = vsum;
      }
    }
  }
}

// ---------- kernel 3: merge partials -> loss ----------
__global__ void arc_reduce_kernel(const float* __restrict__ pmax,
                                  const float* __restrict__ psum,
                                  const float* __restrict__ lbl_logit,
                                  float* __restrict__ out) {
  const int row  = blockIdx.x;
  const int lane = threadIdx.x;   // 64 threads
  const float* pm = pmax + (size_t)row * NPART;
  const float* ps = psum + (size_t)row * NPART;
  float m = -1e30f, s = 0.f;
  for (int p = lane; p < NPART; p += 64) {
    float om = pm[p], os = ps[p];
    float nm = fmaxf(m, om);
    s = s * __expf(m - nm) + os * __expf(om - nm);
    m = nm;
  }
  #pragma unroll
  for (int off = 32; off >= 1; off >>= 1) {
    float om = __shfl_xor(m, off, 64);
    float os = __shfl_xor(s, off, 64);
    float nm = fmaxf(m, om);
    s = s * __expf(m - nm) + os * __expf(om - nm);
    m = nm;
  }
  if (lane == 0) {
    float lse = m + logf(s);
    atomicAdd(out, (lse - lbl_logit[row]) * (1.0f / (float)B_ROWS));
  }
}

// ---------- launch ----------
extern "C" void kernel_launch(void* const* d_in, const int* in_sizes, int n_in,
                              void* d_out, int out_size, void* d_ws, size_t ws_size,
                              hipStream_t stream) {
  const float* x      = (const float*)d_in[0];
  const float* W      = (const float*)d_in[1];
  const int*   labels = (const int*)d_in[2];
  float* out = (float*)d_out;

  char* ws = (char*)d_ws;
  unsigned short* nx = (unsigned short*)ws;                                   // 2 MB
  unsigned short* nw = (unsigned short*)(ws + (size_t)B_ROWS * D_DIM * 2);    // 32.75 MB
  char* p = ws + (size_t)B_ROWS * D_DIM * 2 + (size_t)V_COLS * D_DIM * 2;
  float* pmax = (float*)p;  p += (size_t)B_ROWS * NPART * 4;                  // 4.1 MB
  float* psum = (float*)p;  p += (size_t)B_ROWS * NPART * 4;                  // 4.1 MB
  float* lbl_logit = (float*)p;                                               // 8 KB

  hipLaunchKernelGGL(fused_norm_kernel, dim3((B_ROWS + V_COLS) / 4), dim3(256), 0, stream,
                     x, W, nx, nw, out);
  hipLaunchKernelGGL(arc_gemm_kernel, dim3(32 * 16 * 8), dim3(256), 0, stream,
                     nx, nw, labels, pmax, psum, lbl_logit);
  hipLaunchKernelGGL(arc_reduce_kernel, dim3(B_ROWS), dim3(64), 0, stream,
                     pmax, psum, lbl_logit, out);
}

// Round 4
// 216.451 us; speedup vs baseline: 1.2928x; 1.1805x over previous
//
#include <hip/hip_runtime.h>
#include <hip/hip_bf16.h>
#include <math.h>
#include <stdint.h>

#define B_ROWS 2048
#define D_DIM  512
#define V_COLS 32000
#define BM 128
#define BN 128
#define BK 32
#define KSTEPS (D_DIM / BK)             // 16
#define NCT    (V_COLS / BN)            // 250 col tiles
#define TILE_E (BM * BK)                // 4096 elems per LDS buffer
#define S_SC   30.0f
#define COS_M  0.8775825618903728f      // cos(0.5)
#define SIN_M  0.479425538604203f       // sin(0.5)

typedef __bf16 bf16x8 __attribute__((ext_vector_type(8)));
typedef float  f32x4  __attribute__((ext_vector_type(4)));

// ---------- helpers ----------
__device__ __forceinline__ unsigned short f2bf(float f) {
  union { float f; unsigned u; } v; v.f = f;
  unsigned r = v.u + 0x7fffu + ((v.u >> 16) & 1u);   // round-nearest-even
  return (unsigned short)(r >> 16);
}

__device__ __forceinline__ void load16_to_lds(const void* g, void* l) {
  __builtin_amdgcn_global_load_lds(
      (__attribute__((address_space(1))) void*)(g),
      (__attribute__((address_space(3))) void*)(l),
      16, 0, 0);
}

// ---------- kernel 1: fused L2-normalize (x,W) fp32->bf16 + zero out/rowsum ----------
__global__ void fused_norm_kernel(const float* __restrict__ x,
                                  const float* __restrict__ W,
                                  unsigned short* __restrict__ nx,
                                  unsigned short* __restrict__ nw,
                                  float* __restrict__ rowsum,
                                  float* __restrict__ out) {
  if (blockIdx.x == 0 && threadIdx.x == 0) out[0] = 0.f;
  if (blockIdx.x < B_ROWS / 256) rowsum[blockIdx.x * 256 + threadIdx.x] = 0.f;
  const int lane = threadIdx.x & 63;
  const int wave = threadIdx.x >> 6;
  const int gr   = blockIdx.x * 4 + wave;
  const float* src;
  unsigned short* dst;
  if (gr < B_ROWS) {
    src = x + (size_t)gr * D_DIM;
    dst = nx + (size_t)gr * D_DIM;
  } else {
    src = W + (size_t)(gr - B_ROWS) * D_DIM;
    dst = nw + (size_t)(gr - B_ROWS) * D_DIM;
  }
  const float4* r4 = (const float4*)src;
  float4 v0 = r4[lane];
  float4 v1 = r4[64 + lane];
  float ss = v0.x*v0.x + v0.y*v0.y + v0.z*v0.z + v0.w*v0.w
           + v1.x*v1.x + v1.y*v1.y + v1.z*v1.z + v1.w*v1.w;
  #pragma unroll
  for (int off = 32; off >= 1; off >>= 1) ss += __shfl_xor(ss, off, 64);
  float inv = 1.0f / fmaxf(sqrtf(ss), 1e-12f);
  ushort4 o0, o1;
  o0.x = f2bf(v0.x*inv); o0.y = f2bf(v0.y*inv); o0.z = f2bf(v0.z*inv); o0.w = f2bf(v0.w*inv);
  o1.x = f2bf(v1.x*inv); o1.y = f2bf(v1.y*inv); o1.z = f2bf(v1.z*inv); o1.w = f2bf(v1.w*inv);
  ushort4* d4 = (ushort4*)dst;
  d4[lane]      = o0;
  d4[64 + lane] = o1;
}

// ---------- kernel 2: bf16 GEMM (nx @ nW^T) + label-phi + fixed-shift exp-sum ----------
// Grid: 1D 4096; ct = (id>>7)*8 + (id&7) (XCD-exclusive col tiles), rt = (id>>3)&15
//   fastest -> each XCD's nw tile stays L2-hot across 16 row tiles. FETCH ~50 MB (R3).
// LDS: double-buffered BK=32 tiles (32 KB total), one barrier per K-step; prefetch of
//   tile k+1 issued right after the barrier, drained at the NEXT barrier (full compute
//   phase of overlap vs 0 in R3). XOR bank swizzle as R3 (measured 0 conflicts).
// Softmax: logits bounded by |S|=30 -> fixed shift 30, partial = sum exp(v-30);
//   quad-reduced and atomicAdd'ed into rowsum[2048] (no max pass, no partial arrays).
__global__ __launch_bounds__(256, 4)
void arc_gemm_kernel(const unsigned short* __restrict__ nx,
                     const unsigned short* __restrict__ nw,
                     const int* __restrict__ labels,
                     float* __restrict__ rowsum,
                     float* __restrict__ lbl_logit) {
  __shared__ unsigned short sA[2 * TILE_E];   // 16 KB
  __shared__ unsigned short sB[2 * TILE_E];   // 16 KB

  const int id = blockIdx.x;
  const int ct = ((id >> 7) << 3) | (id & 7);
  if (ct >= NCT) return;
  const int rt = (id >> 3) & 15;
  const int m0 = rt * BM;
  const int n0 = ct * BN;

  const int tid  = threadIdx.x;
  const int wave = tid >> 6;
  const int lane = tid & 63;
  const int wm   = wave >> 1;
  const int wn   = wave & 1;
  const int quad = lane >> 4;
  const int l16  = lane & 15;

  // staging addresses: thread stages rows {sr, 64+sr}, LDS slot col js <- global chunk jg
  const int js = tid & 3;
  const int sr = tid >> 2;
  const int jg = js ^ ((sr >> 1) & 3);
  const unsigned short* gA  = nx + (size_t)(m0 + sr) * D_DIM + jg * 8;
  const unsigned short* gA2 = gA + 64 * D_DIM;
  const unsigned short* gB  = nw + (size_t)(n0 + sr) * D_DIM + jg * 8;
  const unsigned short* gB2 = gB + 64 * D_DIM;
  const int wbase = wave * 512;            // wave-uniform LDS chunk base (elems)

  // fragment-load swizzle (lane-constant), validated 0-conflict in R3
  const int cSlot = ((quad ^ ((l16 >> 1) & 3)) << 3);
  const int arow = (wm * 64 + l16) * BK + cSlot;   // + mi*16*BK imm
  const int brow = (wn * 64 + l16) * BK + cSlot;

  f32x4 acc[4][4];
  #pragma unroll
  for (int i = 0; i < 4; ++i)
    #pragma unroll
    for (int j = 0; j < 4; ++j) acc[i][j] = (f32x4){0.f, 0.f, 0.f, 0.f};

  // prologue: stage tile 0 into buffer 0
  load16_to_lds(gA, &sA[wbase]);
  load16_to_lds(gA2, &sA[2048 + wbase]);
  load16_to_lds(gB, &sB[wbase]);
  load16_to_lds(gB2, &sB[2048 + wbase]);

  #pragma unroll
  for (int ks = 0; ks < KSTEPS; ++ks) {
    __syncthreads();                       // tile ks resident; buf[nxt] readers done
    if (ks + 1 < KSTEPS) {                 // prefetch tile ks+1 -> alternate buffer
      const int off = (ks + 1) * BK;
      const int bo  = ((ks + 1) & 1) * TILE_E;
      load16_to_lds(gA + off, &sA[bo + wbase]);
      load16_to_lds(gA2 + off, &sA[bo + 2048 + wbase]);
      load16_to_lds(gB + off, &sB[bo + wbase]);
      load16_to_lds(gB2 + off, &sB[bo + 2048 + wbase]);
    }
    const int bo = (ks & 1) * TILE_E;
    bf16x8 af[4], bfr[4];
    #pragma unroll
    for (int mi = 0; mi < 4; ++mi)
      af[mi] = *(const bf16x8*)&sA[bo + arow + mi * 16 * BK];
    #pragma unroll
    for (int ni = 0; ni < 4; ++ni)
      bfr[ni] = *(const bf16x8*)&sB[bo + brow + ni * 16 * BK];
    #pragma unroll
    for (int mi = 0; mi < 4; ++mi)
      #pragma unroll
      for (int ni = 0; ni < 4; ++ni)
        acc[mi][ni] = __builtin_amdgcn_mfma_f32_16x16x32_bf16(af[mi], bfr[ni], acc[mi][ni], 0, 0, 0);
  }

  // Epilogue. C/D layout: col = lane&15, row = quad*4 + reg.
  const int lblv = labels[m0 + wm * 64 + lane];   // wave's 64 row labels, one per lane
  #pragma unroll
  for (int mi = 0; mi < 4; ++mi) {
    #pragma unroll
    for (int r = 0; r < 4; ++r) {
      const int rw   = mi * 16 + quad * 4 + r;    // row within wave's 64
      const int grow = m0 + wm * 64 + rw;
      const int lbl  = __shfl(lblv, rw, 64);
      float rsum = 0.f;
      #pragma unroll
      for (int ni = 0; ni < 4; ++ni) {
        float c = acc[mi][ni][r];
        const int gcol = n0 + wn * 64 + ni * 16 + l16;
        if (gcol == lbl) {
          float sy  = sqrtf(fminf(1.f, fmaxf(0.f, 1.f - c * c)));
          float phi = c * COS_M - sy * SIN_M;
          lbl_logit[grow] = S_SC * phi;           // exactly one lane grid-wide
          c = phi;
        }
        rsum += __expf(S_SC * c - 30.0f);         // fixed shift: logits in [-30,30]
      }
      #pragma unroll
      for (int off = 1; off < 16; off <<= 1)
        rsum += __shfl_xor(rsum, off, 64);
      if (l16 == 0) atomicAdd(&rowsum[grow], rsum);
    }
  }
}

// ---------- kernel 3: per-row loss + global mean ----------
__global__ void arc_finish_kernel(const float* __restrict__ rowsum,
                                  const float* __restrict__ lbl_logit,
                                  float* __restrict__ out) {
  const int row  = blockIdx.x * 256 + threadIdx.x;   // 8 blocks x 256
  const int lane = threadIdx.x & 63;
  const int wave = threadIdx.x >> 6;
  float v = (30.0f + logf(rowsum[row]) - lbl_logit[row]) * (1.0f / (float)B_ROWS);
  #pragma unroll
  for (int off = 32; off >= 1; off >>= 1) v += __shfl_xor(v, off, 64);
  __shared__ float wsum[4];
  if (lane == 0) wsum[wave] = v;
  __syncthreads();
  if (threadIdx.x == 0) atomicAdd(out, wsum[0] + wsum[1] + wsum[2] + wsum[3]);
}

// ---------- launch ----------
extern "C" void kernel_launch(void* const* d_in, const int* in_sizes, int n_in,
                              void* d_out, int out_size, void* d_ws, size_t ws_size,
                              hipStream_t stream) {
  const float* x      = (const float*)d_in[0];
  const float* W      = (const float*)d_in[1];
  const int*   labels = (const int*)d_in[2];
  float* out = (float*)d_out;

  char* ws = (char*)d_ws;
  unsigned short* nx = (unsigned short*)ws;                                   // 2 MB
  unsigned short* nw = (unsigned short*)(ws + (size_t)B_ROWS * D_DIM * 2);    // 32.75 MB
  char* p = ws + (size_t)B_ROWS * D_DIM * 2 + (size_t)V_COLS * D_DIM * 2;
  float* rowsum    = (float*)p;  p += (size_t)B_ROWS * 4;                     // 8 KB
  float* lbl_logit = (float*)p;                                               // 8 KB

  hipLaunchKernelGGL(fused_norm_kernel, dim3((B_ROWS + V_COLS) / 4), dim3(256), 0, stream,
                     x, W, nx, nw, rowsum, out);
  hipLaunchKernelGGL(arc_gemm_kernel, dim3(32 * 16 * 8), dim3(256), 0, stream,
                     nx, nw, labels, rowsum, lbl_logit);
  hipLaunchKernelGGL(arc_finish_kernel, dim3(B_ROWS / 256), dim3(256), 0, stream,
                     rowsum, lbl_logit, out);
}